// Round 8
// baseline (330.021 us; speedup 1.0000x reference)
//
#include <hip/hip_runtime.h>
#include <hip/hip_bf16.h>

#define BN 4
#define TT 2305
#define CC 384
#define HH 6
#define DH 64
#define GW 48
#define BH (BN*HH)          // 24
#define TP 2368             // 37*64, padded T for K/V
#define TQP 2560            // q buffer rows (10*256 coverage)
#define MF 9220             // BN*TT flattened tokens
#define MP 9344             // 73*128 padded
#define MB2 73              // m-blocks of 128 in out_gemm
#define NSPL 3              // flash split-K
#define C2 0.07362223f      // 384^-0.5 * log2(e)

typedef __hip_bfloat16 bf16;
typedef __attribute__((ext_vector_type(8))) short short8;
typedef __attribute__((ext_vector_type(4))) float floatx4;
typedef __attribute__((ext_vector_type(16))) float floatx16;

#define MFMA16(a,b,c) __builtin_amdgcn_mfma_f32_16x16x32_bf16((a),(b),(c),0,0,0)
#define MFMA32(a,b,c) __builtin_amdgcn_mfma_f32_32x32x16_bf16((a),(b),(c),0,0,0)

__device__ __forceinline__ unsigned pack2(float a, float b) {
    bf16 lo = __float2bfloat16(a);
    bf16 hi = __float2bfloat16(b);
    unsigned short ul = *reinterpret_cast<unsigned short*>(&lo);
    unsigned short uh = *reinterpret_cast<unsigned short*>(&hi);
    return (unsigned)ul | ((unsigned)uh << 16);
}
__device__ __forceinline__ float bu2f(unsigned u16) {
    unsigned v = u16 << 16;
    return *reinterpret_cast<float*>(&v);
}

// ---------------------------------------------------------------------------
// K1: depthwise conv3x3 + BN (+ cls passthrough) + fused fp32->bf16 weight cvt.
// ---------------------------------------------------------------------------
__global__ __launch_bounds__(384)
void conv_bn(const float* __restrict__ x,
             const float* __restrict__ kq, const float* __restrict__ kk, const float* __restrict__ kv,
             const float* __restrict__ gq, const float* __restrict__ bq, const float* __restrict__ mq, const float* __restrict__ vq,
             const float* __restrict__ gk, const float* __restrict__ bk, const float* __restrict__ mk, const float* __restrict__ vk,
             const float* __restrict__ gv, const float* __restrict__ bv, const float* __restrict__ mv, const float* __restrict__ vv,
             const float* __restrict__ Wq, const float* __restrict__ Wk,
             const float* __restrict__ Wv, const float* __restrict__ Wo,
             bf16* __restrict__ wqb, bf16* __restrict__ wkb,
             bf16* __restrict__ wvb, bf16* __restrict__ wob,
             bf16* __restrict__ cq, bf16* __restrict__ ck, bf16* __restrict__ cv)
{
    // fused weight conversion (first 384 blocks cover 147456 elems)
    {
        const int i = blockIdx.x * 384 + threadIdx.x;
        if (i < CC * CC) {
            wqb[i] = __float2bfloat16(Wq[i]);
            wkb[i] = __float2bfloat16(Wk[i]);
            wvb[i] = __float2bfloat16(Wv[i]);
            wob[i] = __float2bfloat16(Wo[i]);
        }
    }

    const int n = blockIdx.x;
    const int b = n / 289;
    const int t0 = (n % 289) * 8;
    const int c = threadIdx.x;
    const size_t xbase = (size_t)b * TT * CC;

    const float sq = gq[c] * rsqrtf(vq[c] + 1e-5f), oq = bq[c] - mq[c] * sq;
    const float sk = gk[c] * rsqrtf(vk[c] + 1e-5f), ok = bk[c] - mk[c] * sk;
    const float sv = gv[c] * rsqrtf(vv[c] + 1e-5f), ov = bv[c] - mv[c] * sv;
    float wq9[9], wk9[9], wv9[9];
    #pragma unroll
    for (int u = 0; u < 9; u++) {
        wq9[u] = kq[c * 9 + u]; wk9[u] = kk[c * 9 + u]; wv9[u] = kv[c * 9 + u];
    }

    for (int g = 0; g < 8; g++) {
        const int t = t0 + g;
        if (t >= TT) break;
        const size_t mrow = (size_t)(b * TT + t) * CC + c;
        if (t == 0) {
            bf16 xv = __float2bfloat16(x[xbase + c]);
            cq[mrow] = xv; ck[mrow] = xv; cv[mrow] = xv;
        } else {
            const int s = t - 1, i = s / GW, j = s % GW;
            float aq = 0.f, ak = 0.f, av = 0.f;
            #pragma unroll
            for (int di = 0; di < 3; di++) {
                int ii = i + di - 1;
                if (ii < 0 || ii >= GW) continue;
                #pragma unroll
                for (int dj = 0; dj < 3; dj++) {
                    int jj = j + dj - 1;
                    if (jj < 0 || jj >= GW) continue;
                    float xv = x[xbase + (size_t)(1 + ii * GW + jj) * CC + c];
                    int u = di * 3 + dj;
                    aq += xv * wq9[u]; ak += xv * wk9[u]; av += xv * wv9[u];
                }
            }
            cq[mrow] = __float2bfloat16(aq * sq + oq);
            ck[mrow] = __float2bfloat16(ak * sk + ok);
            cv[mrow] = __float2bfloat16(av * sv + ov);
        }
    }
}

// ---------------------------------------------------------------------------
// K2: QKV projection GEMM, per-batch 256-row m-tiles (4 strips share B-frags).
// grid = (40 = 4 batches x 10 tiles, 18 n-tiles). V gets an LDS-transpose
// epilogue for coalesced vT stores.
// ---------------------------------------------------------------------------
__global__ __launch_bounds__(256)
void qkv_gemm(const bf16* __restrict__ cq, const bf16* __restrict__ ck, const bf16* __restrict__ cv,
              const bf16* __restrict__ Wq, const bf16* __restrict__ Wk, const bf16* __restrict__ Wv,
              bf16* __restrict__ q, bf16* __restrict__ k, bf16* __restrict__ vT)
{
    const int bt = blockIdx.x;
    const int b = bt / 10;
    const int m0 = (bt % 10) * 256;       // token index within batch
    const int n0 = blockIdx.y * 64;
    const int w = threadIdx.x >> 6, lane = threadIdx.x & 63;
    const int lm = lane & 15, q4 = lane >> 4;
    const int which = n0 / CC;
    const int obase = n0 % CC;
    const bf16* A = (which == 0) ? cq : (which == 1) ? ck : cv;
    const bf16* W = (which == 0) ? Wq : (which == 1) ? Wk : Wv;

    __shared__ __align__(16) bf16 TR[64 * 264];

    size_t arow[4];
    #pragma unroll
    for (int st = 0; st < 4; st++) {
        int t = m0 + st * 64 + w * 16 + lm;
        if (t >= TT) t = TT - 1;          // clamp; masked at store
        arow[st] = (size_t)(b * TT + t) * CC;
    }

    floatx4 acc[4][4];
    #pragma unroll
    for (int st = 0; st < 4; st++)
        #pragma unroll
        for (int n = 0; n < 4; n++) acc[st][n] = (floatx4){0.f, 0.f, 0.f, 0.f};

    #pragma unroll 2
    for (int kc = 0; kc < CC / 32; kc++) {
        short8 a[4];
        #pragma unroll
        for (int st = 0; st < 4; st++)
            a[st] = *(const short8*)(A + arow[st] + kc * 32 + q4 * 8);
        #pragma unroll
        for (int n = 0; n < 4; n++) {
            short8 bfr = *(const short8*)(W + (size_t)(obase + n * 16 + lm) * CC + kc * 32 + q4 * 8);
            #pragma unroll
            for (int st = 0; st < 4; st++)
                acc[st][n] = MFMA16(a[st], bfr, acc[st][n]);
        }
    }

    if (which == 2) {
        // transpose via LDS: TR[o_local][m_local], stride 264
        #pragma unroll
        for (int st = 0; st < 4; st++)
            #pragma unroll
            for (int n = 0; n < 4; n++) {
                const int ol = n * 16 + lm;
                const int ml = st * 64 + w * 16 + q4 * 4;
                uint2 pkd = { pack2(acc[st][n][0], acc[st][n][1]),
                              pack2(acc[st][n][2], acc[st][n][3]) };
                *(uint2*)&TR[ol * 264 + ml] = pkd;
            }
        __syncthreads();
        const int h = obase >> 6;
        const int o = threadIdx.x >> 2;       // d in [0,64)
        const int seg = threadIdx.x & 3;      // 64 m per seg
        const size_t vrow = ((size_t)(b * HH + h) * DH + o) * TP;
        #pragma unroll
        for (int j = 0; j < 8; j++) {
            const int ml = seg * 64 + j * 8;
            const int t = m0 + ml;
            uint4 val = *(const uint4*)&TR[o * 264 + ml];
            if (t + 8 <= TT) {
                *(uint4*)(vT + vrow + t) = val;
            } else if (t < TT) {
                const bf16* pv = (const bf16*)&val;
                for (int e = 0; e < 8 && t + e < TT; e++) vT[vrow + t + e] = pv[e];
            }
        }
    } else {
        #pragma unroll
        for (int st = 0; st < 4; st++)
            #pragma unroll
            for (int n = 0; n < 4; n++) {
                const int o = obase + n * 16 + lm;
                const int h = o >> 6, d = o & 63;
                #pragma unroll
                for (int r = 0; r < 4; r++) {
                    const int t = m0 + st * 64 + w * 16 + q4 * 4 + r;
                    if (t >= TT) continue;
                    bf16 val = __float2bfloat16(acc[st][n][r]);
                    if (which == 0)
                        q[((size_t)(b * HH + h) * TQP + t) * DH + d] = val;
                    else
                        k[((size_t)(b * HH + h) * TP + t) * DH + d] = val;
                }
            }
    }
}

// ---------------------------------------------------------------------------
// K3: flash attention, split-K x3, LDS double-buffered, 3 blocks/CU.
// grid = (10, 24 bh, 3 splits). Writes unnormalized O (bf16) + m,l (fp32).
// V frags read from LDS inside the PV loop (cuts 16 live VGPRs so 720
// blocks stay co-resident at 3 blocks/CU).
// ---------------------------------------------------------------------------
__global__ __launch_bounds__(256, 3)
void flash(const bf16* __restrict__ q, const bf16* __restrict__ k,
           const bf16* __restrict__ vT, bf16* __restrict__ OP, float* __restrict__ ML)
{
    const int bh = blockIdx.y;
    const int z = blockIdx.z;
    const int tid = threadIdx.x;
    const int w = tid >> 6, lane = tid & 63;
    const int q31 = lane & 31, hh = lane >> 5;
    const int q0 = blockIdx.x * 256 + w * 64;
    const size_t kbase = (size_t)bh * TP * DH;
    const size_t qbase = (size_t)bh * TQP * DH;

    __shared__ __align__(16) bf16 Ks[2][64 * 64];
    __shared__ __align__(16) bf16 Vs[2][64 * 64];

    short8 qf[2][4];
    #pragma unroll
    for (int s = 0; s < 2; s++) {
        const bf16* qrow = q + qbase + (size_t)(q0 + s * 32 + q31) * DH;
        #pragma unroll
        for (int kc = 0; kc < 4; kc++)
            qf[s][kc] = *(const short8*)(qrow + kc * 16 + hh * 8);
    }

    floatx16 of[2][2];
    #pragma unroll
    for (int s = 0; s < 2; s++)
        #pragma unroll
        for (int dt = 0; dt < 2; dt++)
            #pragma unroll
            for (int r = 0; r < 16; r++) of[s][dt][r] = 0.f;
    float m2[2] = {-1e30f, -1e30f}, lsum[2] = {0.f, 0.f};

    const int tstart = (z == 0) ? 0 : (z == 1) ? 13 : 25;
    const int tend   = (z == 0) ? 13 : (z == 1) ? 25 : 37;

    const int tr0 = tid >> 3,          c80 = tid & 7;
    const int tr1 = (tid + 256) >> 3,  c81 = tid & 7;
    const int so0 = tr0 * 64 + ((c80 ^ (tr0 & 7)) * 8);
    const int so1 = tr1 * 64 + ((c81 ^ (tr1 & 7)) * 8);

    uint4 kreg[2], vreg[2];
    {
        const int t0 = tstart * 64;
        kreg[0] = *(const uint4*)(k + kbase + (size_t)(t0 + tr0) * DH + c80 * 8);
        vreg[0] = *(const uint4*)(vT + kbase + (size_t)tr0 * TP + t0 + c80 * 8);
        kreg[1] = *(const uint4*)(k + kbase + (size_t)(t0 + tr1) * DH + c81 * 8);
        vreg[1] = *(const uint4*)(vT + kbase + (size_t)tr1 * TP + t0 + c81 * 8);
    }
    *(uint4*)&Ks[0][so0] = kreg[0];
    *(uint4*)&Vs[0][so0] = vreg[0];
    *(uint4*)&Ks[0][so1] = kreg[1];
    *(uint4*)&Vs[0][so1] = vreg[1];

    for (int tc = tstart; tc < tend; tc++) {
        const int cur = (tc - tstart) & 1;
        const int t0 = tc * 64;
        __syncthreads();
        const bool more = (tc + 1 < tend);
        if (more) {
            const int t1 = t0 + 64;
            kreg[0] = *(const uint4*)(k + kbase + (size_t)(t1 + tr0) * DH + c80 * 8);
            vreg[0] = *(const uint4*)(vT + kbase + (size_t)tr0 * TP + t1 + c80 * 8);
            kreg[1] = *(const uint4*)(k + kbase + (size_t)(t1 + tr1) * DH + c81 * 8);
            vreg[1] = *(const uint4*)(vT + kbase + (size_t)tr1 * TP + t1 + c81 * 8);
        }
        const bf16* Kc = Ks[cur];
        const bf16* Vc = Vs[cur];

        short8 ka[2][4];
        #pragma unroll
        for (int mt = 0; mt < 2; mt++)
            #pragma unroll
            for (int kc = 0; kc < 4; kc++) {
                const int row = mt * 32 + q31, c = 2 * kc + hh;
                ka[mt][kc] = *(const short8*)&Kc[row * 64 + ((c ^ (row & 7)) * 8)];
            }
        const bool tail = (t0 + 64 > TT);

        #pragma unroll
        for (int s = 0; s < 2; s++) {
            floatx16 sv[2];
            #pragma unroll
            for (int mt = 0; mt < 2; mt++)
                #pragma unroll
                for (int r = 0; r < 16; r++) sv[mt][r] = 0.f;
            #pragma unroll
            for (int kc = 0; kc < 4; kc++) {
                sv[0] = MFMA32(ka[0][kc], qf[s][kc], sv[0]);
                sv[1] = MFMA32(ka[1][kc], qf[s][kc], sv[1]);
            }
            if (tail) {
                #pragma unroll
                for (int mt = 0; mt < 2; mt++)
                    #pragma unroll
                    for (int r = 0; r < 16; r++) {
                        const int tl = t0 + mt * 32 + (r & 3) + 8 * (r >> 2) + 4 * hh;
                        if (tl >= TT) sv[mt][r] = -1e30f;
                    }
            }
            float rm = sv[0][0];
            #pragma unroll
            for (int r = 1; r < 16; r++) rm = fmaxf(rm, sv[0][r]);
            #pragma unroll
            for (int r = 0; r < 16; r++) rm = fmaxf(rm, sv[1][r]);
            rm = fmaxf(rm, __shfl_xor(rm, 32));
            const float mn = fmaxf(m2[s], rm * C2);
            const float alpha = __builtin_amdgcn_exp2f(m2[s] - mn);
            m2[s] = mn;
            const float negm = -mn;
            float rs = 0.f;
            unsigned pk[2][8];
            #pragma unroll
            for (int mt = 0; mt < 2; mt++)
                #pragma unroll
                for (int p = 0; p < 8; p++) {
                    const float p0 = __builtin_amdgcn_exp2f(fmaf(sv[mt][2 * p], C2, negm));
                    const float p1 = __builtin_amdgcn_exp2f(fmaf(sv[mt][2 * p + 1], C2, negm));
                    rs += p0 + p1;
                    pk[mt][p] = pack2(p0, p1);
                }
            rs += __shfl_xor(rs, 32);
            lsum[s] = lsum[s] * alpha + rs;
            #pragma unroll
            for (int dt = 0; dt < 2; dt++)
                #pragma unroll
                for (int r = 0; r < 16; r++) of[s][dt][r] *= alpha;

            #pragma unroll
            for (int kc = 0; kc < 4; kc++) {
                const int u0 = 2 * kc, u1 = 2 * kc + 1;
                const unsigned P0a = pk[u0 >> 2][2 * (u0 & 3)];
                const unsigned P0b = pk[u0 >> 2][2 * (u0 & 3) + 1];
                const unsigned P1a = pk[u1 >> 2][2 * (u1 & 3)];
                const unsigned P1b = pk[u1 >> 2][2 * (u1 & 3) + 1];
                const unsigned X1 = hh ? P0a : P1a;
                const unsigned X2 = hh ? P0b : P1b;
                const unsigned Y1 = __shfl_xor(X1, 32);
                const unsigned Y2 = __shfl_xor(X2, 32);
                unsigned dw[4];
                dw[0] = hh ? Y1 : P0a;
                dw[1] = hh ? Y2 : P0b;
                dw[2] = hh ? P1a : Y1;
                dw[3] = hh ? P1b : Y2;
                short8 pb = *reinterpret_cast<short8*>(dw);
                const int c = 2 * kc + hh;
                const int row0 = q31, row1 = 32 + q31;
                short8 va0 = *(const short8*)&Vc[row0 * 64 + ((c ^ (row0 & 7)) * 8)];
                short8 va1 = *(const short8*)&Vc[row1 * 64 + ((c ^ (row1 & 7)) * 8)];
                of[s][0] = MFMA32(va0, pb, of[s][0]);
                of[s][1] = MFMA32(va1, pb, of[s][1]);
            }
        }

        if (more) {
            bf16* Kn = Ks[1 - cur];
            bf16* Vn = Vs[1 - cur];
            *(uint4*)&Kn[so0] = kreg[0];
            *(uint4*)&Vn[so0] = vreg[0];
            *(uint4*)&Kn[so1] = kreg[1];
            *(uint4*)&Vn[so1] = vreg[1];
        }
    }

    // store unnormalized partials (rows packed to TT per (z,bh))
    #pragma unroll
    for (int s = 0; s < 2; s++) {
        const int qrow = q0 + s * 32 + q31;
        if (qrow >= TT) continue;
        bf16* orow = OP + ((size_t)(z * BH + bh) * TT + qrow) * DH;
        #pragma unroll
        for (int dt = 0; dt < 2; dt++)
            #pragma unroll
            for (int p = 0; p < 4; p++) {
                const int d = dt * 32 + 8 * p + 4 * hh;
                unsigned lo = pack2(of[s][dt][4 * p], of[s][dt][4 * p + 1]);
                unsigned hi = pack2(of[s][dt][4 * p + 2], of[s][dt][4 * p + 3]);
                uint2 st = {lo, hi};
                *(uint2*)(orow + d) = st;
            }
        if (hh == 0) {
            float2 ml = {m2[s], lsum[s]};
            *(float2*)&ML[((size_t)(z * BH + bh) * TT + qrow) * 2] = ml;
        }
    }
}

// ---------------------------------------------------------------------------
// K3b: merge the three split-K partials -> att (bf16, head-major cols).
// ---------------------------------------------------------------------------
__global__ __launch_bounds__(256)
void merge(const bf16* __restrict__ OP, const float* __restrict__ ML,
           bf16* __restrict__ att)
{
    const int idx = blockIdx.x * 256 + threadIdx.x;
    if (idx >= BH * TT * 16) return;
    const int quad = idx & 15;
    const int pair = idx >> 4;
    const int bh = pair / TT, row = pair % TT;
    const int b = bh / HH, h = bh % HH;
    const int d0 = quad * 4;

    float2 ml[NSPL];
    #pragma unroll
    for (int z = 0; z < NSPL; z++)
        ml[z] = *(const float2*)&ML[((size_t)(z * BH + bh) * TT + row) * 2];
    float M = ml[0].x;
    #pragma unroll
    for (int z = 1; z < NSPL; z++) M = fmaxf(M, ml[z].x);
    float wz[NSPL], den = 0.f;
    #pragma unroll
    for (int z = 0; z < NSPL; z++) {
        wz[z] = __builtin_amdgcn_exp2f(ml[z].x - M);
        den += ml[z].y * wz[z];
    }
    const float inv = 1.f / den;

    float o0 = 0.f, o1 = 0.f, o2 = 0.f, o3 = 0.f;
    #pragma unroll
    for (int z = 0; z < NSPL; z++) {
        const float s = wz[z] * inv;
        const uint2 a = *(const uint2*)&OP[((size_t)(z * BH + bh) * TT + row) * DH + d0];
        o0 += bu2f(a.x & 0xffffu) * s;
        o1 += bu2f(a.x >> 16)     * s;
        o2 += bu2f(a.y & 0xffffu) * s;
        o3 += bu2f(a.y >> 16)     * s;
    }
    uint2 st = {pack2(o0, o1), pack2(o2, o3)};
    *(uint2*)&att[((size_t)(b * TT + row) * CC) + h * DH + d0] = st;
}

// ---------------------------------------------------------------------------
// K4: output projection GEMM + bias, 128-row m-tiles, fp32 out.
// ---------------------------------------------------------------------------
__global__ __launch_bounds__(256)
void out_gemm(const bf16* __restrict__ att, const bf16* __restrict__ Wo_bf,
              const float* __restrict__ bo, float* __restrict__ out)
{
    const int m0 = blockIdx.x * 128;
    const int n0 = blockIdx.y * 64;
    const int w = threadIdx.x >> 6, lane = threadIdx.x & 63;
    const int lm = lane & 15, q4 = lane >> 4;

    const size_t ar0 = (size_t)(m0 + w * 16 + lm) * CC;
    floatx4 acc[2][4];
    #pragma unroll
    for (int st = 0; st < 2; st++)
        #pragma unroll
        for (int n = 0; n < 4; n++) acc[st][n] = (floatx4){0.f, 0.f, 0.f, 0.f};

    #pragma unroll 4
    for (int kc = 0; kc < CC / 32; kc++) {
        short8 a0 = *(const short8*)(att + ar0 + kc * 32 + q4 * 8);
        short8 a1 = *(const short8*)(att + ar0 + (size_t)64 * CC + kc * 32 + q4 * 8);
        #pragma unroll
        for (int n = 0; n < 4; n++) {
            short8 bfr = *(const short8*)(Wo_bf + (size_t)(n0 + n * 16 + lm) * CC + kc * 32 + q4 * 8);
            acc[0][n] = MFMA16(a0, bfr, acc[0][n]);
            acc[1][n] = MFMA16(a1, bfr, acc[1][n]);
        }
    }

    #pragma unroll
    for (int st = 0; st < 2; st++)
        #pragma unroll
        for (int n = 0; n < 4; n++) {
            const int o = n0 + n * 16 + lm;
            const float bias = bo[o];
            #pragma unroll
            for (int r = 0; r < 4; r++) {
                const int m = m0 + st * 64 + w * 16 + q4 * 4 + r;
                if (m < MF) out[(size_t)m * CC + o] = acc[st][n][r] + bias;
            }
        }
}

// ---------------------------------------------------------------------------
extern "C" void kernel_launch(void* const* d_in, const int* in_sizes, int n_in,
                              void* d_out, int out_size, void* d_ws, size_t ws_size,
                              hipStream_t stream)
{
    const float* x  = (const float*)d_in[0];
    const float* kq = (const float*)d_in[3];
    const float* kk = (const float*)d_in[4];
    const float* kv = (const float*)d_in[5];
    const float* gq = (const float*)d_in[6];
    const float* bq = (const float*)d_in[7];
    const float* mq = (const float*)d_in[8];
    const float* vq = (const float*)d_in[9];
    const float* gk = (const float*)d_in[10];
    const float* bk = (const float*)d_in[11];
    const float* mk = (const float*)d_in[12];
    const float* vk = (const float*)d_in[13];
    const float* gv = (const float*)d_in[14];
    const float* bv = (const float*)d_in[15];
    const float* mv = (const float*)d_in[16];
    const float* vv = (const float*)d_in[17];
    const float* Wq = (const float*)d_in[18];
    const float* Wk = (const float*)d_in[19];
    const float* Wv = (const float*)d_in[20];
    const float* Wo = (const float*)d_in[21];
    const float* bo = (const float*)d_in[22];

    char* ws = (char*)d_ws;
    const size_t SZ_CONV = (size_t)MP * CC * 2;        // 7,176,192
    const size_t SZ_Q    = (size_t)BH * TQP * DH * 2;  // 7,864,320
    const size_t SZ_K    = (size_t)BH * TP * DH * 2;   // 7,274,496
    const size_t SZ_W    = (size_t)CC * CC * 2;        //   294,912
    size_t off = 0;
    bf16* cq   = (bf16*)(ws + off); off += SZ_CONV;
    bf16* ck   = (bf16*)(ws + off); off += SZ_CONV;
    bf16* cv   = (bf16*)(ws + off); off += SZ_CONV;
    bf16* qb   = (bf16*)(ws + off); off += SZ_Q;
    bf16* kb   = (bf16*)(ws + off); off += SZ_K;
    bf16* vTb  = (bf16*)(ws + off); off += SZ_K;
    bf16* attb = (bf16*)(ws + off); off += SZ_CONV;
    bf16* wqb  = (bf16*)(ws + off); off += SZ_W;
    bf16* wkb  = (bf16*)(ws + off); off += SZ_W;
    bf16* wvb  = (bf16*)(ws + off); off += SZ_W;
    bf16* wob  = (bf16*)(ws + off); off += SZ_W;
    // flash partials: OP aliases cq..cv (dead after qkv_gemm), ML in tail
    bf16*  OP = (bf16*)ws;     // 3*24*2305*64*2 = 21,242,880 <= 3*SZ_CONV
    float* ML = (float*)(ws + off); off += (size_t)NSPL * BH * TT * 2 * 4;

    conv_bn<<<BN * 289, 384, 0, stream>>>(x, kq, kk, kv,
                                          gq, bq, mq, vq,
                                          gk, bk, mk, vk,
                                          gv, bv, mv, vv,
                                          Wq, Wk, Wv, Wo,
                                          wqb, wkb, wvb, wob,
                                          cq, ck, cv);
    qkv_gemm<<<dim3(40, 18), 256, 0, stream>>>(cq, ck, cv, wqb, wkb, wvb, qb, kb, vTb);
    flash<<<dim3(10, BH, NSPL), 256, 0, stream>>>(qb, kb, vTb, OP, ML);
    merge<<<(BH * TT * 16 + 255) / 256, 256, 0, stream>>>(OP, ML, attb);
    out_gemm<<<dim3(MB2, 6), 256, 0, stream>>>(attb, wob, bo, (float*)d_out);
}

// Round 9
// 287.286 us; speedup vs baseline: 1.1488x; 1.1488x over previous
//
#include <hip/hip_runtime.h>
#include <hip/hip_bf16.h>

#define BN 4
#define TT 2305
#define CC 384
#define HH 6
#define DH 64
#define GW 48
#define BH (BN*HH)          // 24
#define TP 2368             // 37*64, padded T for K/V
#define TQP 2560            // q buffer rows (10*256 coverage)
#define MF 9220             // BN*TT flattened tokens
#define MP 9344             // 73*128 padded
#define MB2 73              // m-blocks of 128 in out_gemm
#define NSPL 2              // flash split-K
#define C2 0.07362223f      // 384^-0.5 * log2(e)

typedef __hip_bfloat16 bf16;
typedef __attribute__((ext_vector_type(8))) short short8;
typedef __attribute__((ext_vector_type(4))) float floatx4;
typedef __attribute__((ext_vector_type(16))) float floatx16;

#define MFMA16(a,b,c) __builtin_amdgcn_mfma_f32_16x16x32_bf16((a),(b),(c),0,0,0)
#define MFMA32(a,b,c) __builtin_amdgcn_mfma_f32_32x32x16_bf16((a),(b),(c),0,0,0)

__device__ __forceinline__ unsigned pack2(float a, float b) {
    bf16 lo = __float2bfloat16(a);
    bf16 hi = __float2bfloat16(b);
    unsigned short ul = *reinterpret_cast<unsigned short*>(&lo);
    unsigned short uh = *reinterpret_cast<unsigned short*>(&hi);
    return (unsigned)ul | ((unsigned)uh << 16);
}
__device__ __forceinline__ float bu2f(unsigned u16) {
    unsigned v = u16 << 16;
    return *reinterpret_cast<float*>(&v);
}

// ---------------------------------------------------------------------------
// K1: depthwise conv3x3 + BN (+ cls passthrough) + fused fp32->bf16 weight cvt.
// ---------------------------------------------------------------------------
__global__ __launch_bounds__(384)
void conv_bn(const float* __restrict__ x,
             const float* __restrict__ kq, const float* __restrict__ kk, const float* __restrict__ kv,
             const float* __restrict__ gq, const float* __restrict__ bq, const float* __restrict__ mq, const float* __restrict__ vq,
             const float* __restrict__ gk, const float* __restrict__ bk, const float* __restrict__ mk, const float* __restrict__ vk,
             const float* __restrict__ gv, const float* __restrict__ bv, const float* __restrict__ mv, const float* __restrict__ vv,
             const float* __restrict__ Wq, const float* __restrict__ Wk,
             const float* __restrict__ Wv, const float* __restrict__ Wo,
             bf16* __restrict__ wqb, bf16* __restrict__ wkb,
             bf16* __restrict__ wvb, bf16* __restrict__ wob,
             bf16* __restrict__ cq, bf16* __restrict__ ck, bf16* __restrict__ cv)
{
    // fused weight conversion (first 384 blocks cover 147456 elems)
    {
        const int i = blockIdx.x * 384 + threadIdx.x;
        if (i < CC * CC) {
            wqb[i] = __float2bfloat16(Wq[i]);
            wkb[i] = __float2bfloat16(Wk[i]);
            wvb[i] = __float2bfloat16(Wv[i]);
            wob[i] = __float2bfloat16(Wo[i]);
        }
    }

    const int n = blockIdx.x;
    const int b = n / 289;
    const int t0 = (n % 289) * 8;
    const int c = threadIdx.x;
    const size_t xbase = (size_t)b * TT * CC;

    const float sq = gq[c] * rsqrtf(vq[c] + 1e-5f), oq = bq[c] - mq[c] * sq;
    const float sk = gk[c] * rsqrtf(vk[c] + 1e-5f), ok = bk[c] - mk[c] * sk;
    const float sv = gv[c] * rsqrtf(vv[c] + 1e-5f), ov = bv[c] - mv[c] * sv;
    float wq9[9], wk9[9], wv9[9];
    #pragma unroll
    for (int u = 0; u < 9; u++) {
        wq9[u] = kq[c * 9 + u]; wk9[u] = kk[c * 9 + u]; wv9[u] = kv[c * 9 + u];
    }

    for (int g = 0; g < 8; g++) {
        const int t = t0 + g;
        if (t >= TT) break;
        const size_t mrow = (size_t)(b * TT + t) * CC + c;
        if (t == 0) {
            bf16 xv = __float2bfloat16(x[xbase + c]);
            cq[mrow] = xv; ck[mrow] = xv; cv[mrow] = xv;
        } else {
            const int s = t - 1, i = s / GW, j = s % GW;
            float aq = 0.f, ak = 0.f, av = 0.f;
            #pragma unroll
            for (int di = 0; di < 3; di++) {
                int ii = i + di - 1;
                if (ii < 0 || ii >= GW) continue;
                #pragma unroll
                for (int dj = 0; dj < 3; dj++) {
                    int jj = j + dj - 1;
                    if (jj < 0 || jj >= GW) continue;
                    float xv = x[xbase + (size_t)(1 + ii * GW + jj) * CC + c];
                    int u = di * 3 + dj;
                    aq += xv * wq9[u]; ak += xv * wk9[u]; av += xv * wv9[u];
                }
            }
            cq[mrow] = __float2bfloat16(aq * sq + oq);
            ck[mrow] = __float2bfloat16(ak * sk + ok);
            cv[mrow] = __float2bfloat16(av * sv + ov);
        }
    }
}

// ---------------------------------------------------------------------------
// K2: QKV projection GEMM, per-batch 256-row m-tiles (4 strips share B-frags).
// grid = (40 = 4 batches x 10 tiles, 18 n-tiles). V gets an LDS-transpose
// epilogue for coalesced vT stores.
// ---------------------------------------------------------------------------
__global__ __launch_bounds__(256)
void qkv_gemm(const bf16* __restrict__ cq, const bf16* __restrict__ ck, const bf16* __restrict__ cv,
              const bf16* __restrict__ Wq, const bf16* __restrict__ Wk, const bf16* __restrict__ Wv,
              bf16* __restrict__ q, bf16* __restrict__ k, bf16* __restrict__ vT)
{
    const int bt = blockIdx.x;
    const int b = bt / 10;
    const int m0 = (bt % 10) * 256;       // token index within batch
    const int n0 = blockIdx.y * 64;
    const int w = threadIdx.x >> 6, lane = threadIdx.x & 63;
    const int lm = lane & 15, q4 = lane >> 4;
    const int which = n0 / CC;
    const int obase = n0 % CC;
    const bf16* A = (which == 0) ? cq : (which == 1) ? ck : cv;
    const bf16* W = (which == 0) ? Wq : (which == 1) ? Wk : Wv;

    __shared__ __align__(16) bf16 TR[64 * 264];

    size_t arow[4];
    #pragma unroll
    for (int st = 0; st < 4; st++) {
        int t = m0 + st * 64 + w * 16 + lm;
        if (t >= TT) t = TT - 1;          // clamp; masked at store
        arow[st] = (size_t)(b * TT + t) * CC;
    }

    floatx4 acc[4][4];
    #pragma unroll
    for (int st = 0; st < 4; st++)
        #pragma unroll
        for (int n = 0; n < 4; n++) acc[st][n] = (floatx4){0.f, 0.f, 0.f, 0.f};

    #pragma unroll 2
    for (int kc = 0; kc < CC / 32; kc++) {
        short8 a[4];
        #pragma unroll
        for (int st = 0; st < 4; st++)
            a[st] = *(const short8*)(A + arow[st] + kc * 32 + q4 * 8);
        #pragma unroll
        for (int n = 0; n < 4; n++) {
            short8 bfr = *(const short8*)(W + (size_t)(obase + n * 16 + lm) * CC + kc * 32 + q4 * 8);
            #pragma unroll
            for (int st = 0; st < 4; st++)
                acc[st][n] = MFMA16(a[st], bfr, acc[st][n]);
        }
    }

    if (which == 2) {
        // transpose via LDS: TR[o_local][m_local], stride 264
        #pragma unroll
        for (int st = 0; st < 4; st++)
            #pragma unroll
            for (int n = 0; n < 4; n++) {
                const int ol = n * 16 + lm;
                const int ml = st * 64 + w * 16 + q4 * 4;
                uint2 pkd = { pack2(acc[st][n][0], acc[st][n][1]),
                              pack2(acc[st][n][2], acc[st][n][3]) };
                *(uint2*)&TR[ol * 264 + ml] = pkd;
            }
        __syncthreads();
        const int h = obase >> 6;
        const int o = threadIdx.x >> 2;       // d in [0,64)
        const int seg = threadIdx.x & 3;      // 64 m per seg
        const size_t vrow = ((size_t)(b * HH + h) * DH + o) * TP;
        #pragma unroll
        for (int j = 0; j < 8; j++) {
            const int ml = seg * 64 + j * 8;
            const int t = m0 + ml;
            uint4 val = *(const uint4*)&TR[o * 264 + ml];
            if (t + 8 <= TT) {
                *(uint4*)(vT + vrow + t) = val;
            } else if (t < TT) {
                const bf16* pv = (const bf16*)&val;
                for (int e = 0; e < 8 && t + e < TT; e++) vT[vrow + t + e] = pv[e];
            }
        }
    } else {
        #pragma unroll
        for (int st = 0; st < 4; st++)
            #pragma unroll
            for (int n = 0; n < 4; n++) {
                const int o = obase + n * 16 + lm;
                const int h = o >> 6, d = o & 63;
                #pragma unroll
                for (int r = 0; r < 4; r++) {
                    const int t = m0 + st * 64 + w * 16 + q4 * 4 + r;
                    if (t >= TT) continue;
                    bf16 val = __float2bfloat16(acc[st][n][r]);
                    if (which == 0)
                        q[((size_t)(b * HH + h) * TQP + t) * DH + d] = val;
                    else
                        k[((size_t)(b * HH + h) * TP + t) * DH + d] = val;
                }
            }
    }
}

// ---------------------------------------------------------------------------
// K3: flash attention, split-K x2, LDS double-buffered, 2 blocks/CU (no
// spills). 1-D grid with id = (qt*NSPL+z)*24 + bh so id%8 == bh%8: all
// blocks of one bh land on one XCD (K/V stays L2-resident, 1.8 MB/XCD).
// Writes unnormalized O (bf16) + m,l (fp32).
// ---------------------------------------------------------------------------
__global__ __launch_bounds__(256, 2)
void flash(const bf16* __restrict__ q, const bf16* __restrict__ k,
           const bf16* __restrict__ vT, bf16* __restrict__ OP, float* __restrict__ ML)
{
    const int id = blockIdx.x;
    const int bh = id % BH;
    const int rest = id / BH;
    const int z = rest % NSPL;
    const int qt = rest / NSPL;
    const int tid = threadIdx.x;
    const int w = tid >> 6, lane = tid & 63;
    const int q31 = lane & 31, hh = lane >> 5;
    const int q0 = qt * 256 + w * 64;
    const size_t kbase = (size_t)bh * TP * DH;
    const size_t qbase = (size_t)bh * TQP * DH;

    __shared__ __align__(16) bf16 Ks[2][64 * 64];
    __shared__ __align__(16) bf16 Vs[2][64 * 64];

    short8 qf[2][4];
    #pragma unroll
    for (int s = 0; s < 2; s++) {
        const bf16* qrow = q + qbase + (size_t)(q0 + s * 32 + q31) * DH;
        #pragma unroll
        for (int kc = 0; kc < 4; kc++)
            qf[s][kc] = *(const short8*)(qrow + kc * 16 + hh * 8);
    }

    floatx16 of[2][2];
    #pragma unroll
    for (int s = 0; s < 2; s++)
        #pragma unroll
        for (int dt = 0; dt < 2; dt++)
            #pragma unroll
            for (int r = 0; r < 16; r++) of[s][dt][r] = 0.f;
    float m2[2] = {-1e30f, -1e30f}, lsum[2] = {0.f, 0.f};

    const int tstart = z ? 19 : 0;
    const int tend   = z ? 37 : 19;

    const int tr0 = tid >> 3,          c80 = tid & 7;
    const int tr1 = (tid + 256) >> 3,  c81 = tid & 7;
    const int so0 = tr0 * 64 + ((c80 ^ (tr0 & 7)) * 8);
    const int so1 = tr1 * 64 + ((c81 ^ (tr1 & 7)) * 8);

    uint4 kreg[2], vreg[2];
    {
        const int t0 = tstart * 64;
        kreg[0] = *(const uint4*)(k + kbase + (size_t)(t0 + tr0) * DH + c80 * 8);
        vreg[0] = *(const uint4*)(vT + kbase + (size_t)tr0 * TP + t0 + c80 * 8);
        kreg[1] = *(const uint4*)(k + kbase + (size_t)(t0 + tr1) * DH + c81 * 8);
        vreg[1] = *(const uint4*)(vT + kbase + (size_t)tr1 * TP + t0 + c81 * 8);
    }
    *(uint4*)&Ks[0][so0] = kreg[0];
    *(uint4*)&Vs[0][so0] = vreg[0];
    *(uint4*)&Ks[0][so1] = kreg[1];
    *(uint4*)&Vs[0][so1] = vreg[1];

    for (int tc = tstart; tc < tend; tc++) {
        const int cur = (tc - tstart) & 1;
        const int t0 = tc * 64;
        __syncthreads();
        const bool more = (tc + 1 < tend);
        if (more) {
            const int t1 = t0 + 64;
            kreg[0] = *(const uint4*)(k + kbase + (size_t)(t1 + tr0) * DH + c80 * 8);
            vreg[0] = *(const uint4*)(vT + kbase + (size_t)tr0 * TP + t1 + c80 * 8);
            kreg[1] = *(const uint4*)(k + kbase + (size_t)(t1 + tr1) * DH + c81 * 8);
            vreg[1] = *(const uint4*)(vT + kbase + (size_t)tr1 * TP + t1 + c81 * 8);
        }
        const bf16* Kc = Ks[cur];
        const bf16* Vc = Vs[cur];

        short8 ka[2][4], va[2][4];
        #pragma unroll
        for (int mt = 0; mt < 2; mt++)
            #pragma unroll
            for (int kc = 0; kc < 4; kc++) {
                const int row = mt * 32 + q31, c = 2 * kc + hh;
                ka[mt][kc] = *(const short8*)&Kc[row * 64 + ((c ^ (row & 7)) * 8)];
                va[mt][kc] = *(const short8*)&Vc[row * 64 + ((c ^ (row & 7)) * 8)];
            }
        const bool tail = (t0 + 64 > TT);

        #pragma unroll
        for (int s = 0; s < 2; s++) {
            floatx16 sv[2];
            #pragma unroll
            for (int mt = 0; mt < 2; mt++)
                #pragma unroll
                for (int r = 0; r < 16; r++) sv[mt][r] = 0.f;
            #pragma unroll
            for (int kc = 0; kc < 4; kc++) {
                sv[0] = MFMA32(ka[0][kc], qf[s][kc], sv[0]);
                sv[1] = MFMA32(ka[1][kc], qf[s][kc], sv[1]);
            }
            if (tail) {
                #pragma unroll
                for (int mt = 0; mt < 2; mt++)
                    #pragma unroll
                    for (int r = 0; r < 16; r++) {
                        const int tl = t0 + mt * 32 + (r & 3) + 8 * (r >> 2) + 4 * hh;
                        if (tl >= TT) sv[mt][r] = -1e30f;
                    }
            }
            float rm = sv[0][0];
            #pragma unroll
            for (int r = 1; r < 16; r++) rm = fmaxf(rm, sv[0][r]);
            #pragma unroll
            for (int r = 0; r < 16; r++) rm = fmaxf(rm, sv[1][r]);
            rm = fmaxf(rm, __shfl_xor(rm, 32));
            const float mn = fmaxf(m2[s], rm * C2);
            const float alpha = __builtin_amdgcn_exp2f(m2[s] - mn);
            m2[s] = mn;
            const float negm = -mn;
            float rs = 0.f;
            unsigned pk[2][8];
            #pragma unroll
            for (int mt = 0; mt < 2; mt++)
                #pragma unroll
                for (int p = 0; p < 8; p++) {
                    const float p0 = __builtin_amdgcn_exp2f(fmaf(sv[mt][2 * p], C2, negm));
                    const float p1 = __builtin_amdgcn_exp2f(fmaf(sv[mt][2 * p + 1], C2, negm));
                    rs += p0 + p1;
                    pk[mt][p] = pack2(p0, p1);
                }
            rs += __shfl_xor(rs, 32);
            lsum[s] = lsum[s] * alpha + rs;
            #pragma unroll
            for (int dt = 0; dt < 2; dt++)
                #pragma unroll
                for (int r = 0; r < 16; r++) of[s][dt][r] *= alpha;

            #pragma unroll
            for (int kc = 0; kc < 4; kc++) {
                const int u0 = 2 * kc, u1 = 2 * kc + 1;
                const unsigned P0a = pk[u0 >> 2][2 * (u0 & 3)];
                const unsigned P0b = pk[u0 >> 2][2 * (u0 & 3) + 1];
                const unsigned P1a = pk[u1 >> 2][2 * (u1 & 3)];
                const unsigned P1b = pk[u1 >> 2][2 * (u1 & 3) + 1];
                const unsigned X1 = hh ? P0a : P1a;
                const unsigned X2 = hh ? P0b : P1b;
                const unsigned Y1 = __shfl_xor(X1, 32);
                const unsigned Y2 = __shfl_xor(X2, 32);
                unsigned dw[4];
                dw[0] = hh ? Y1 : P0a;
                dw[1] = hh ? Y2 : P0b;
                dw[2] = hh ? P1a : Y1;
                dw[3] = hh ? P1b : Y2;
                short8 pb = *reinterpret_cast<short8*>(dw);
                of[s][0] = MFMA32(va[0][kc], pb, of[s][0]);
                of[s][1] = MFMA32(va[1][kc], pb, of[s][1]);
            }
        }

        if (more) {
            bf16* Kn = Ks[1 - cur];
            bf16* Vn = Vs[1 - cur];
            *(uint4*)&Kn[so0] = kreg[0];
            *(uint4*)&Vn[so0] = vreg[0];
            *(uint4*)&Kn[so1] = kreg[1];
            *(uint4*)&Vn[so1] = vreg[1];
        }
    }

    // store unnormalized partials (rows packed to TT per (z,bh))
    #pragma unroll
    for (int s = 0; s < 2; s++) {
        const int qrow = q0 + s * 32 + q31;
        if (qrow >= TT) continue;
        bf16* orow = OP + ((size_t)(z * BH + bh) * TT + qrow) * DH;
        #pragma unroll
        for (int dt = 0; dt < 2; dt++)
            #pragma unroll
            for (int p = 0; p < 4; p++) {
                const int d = dt * 32 + 8 * p + 4 * hh;
                unsigned lo = pack2(of[s][dt][4 * p], of[s][dt][4 * p + 1]);
                unsigned hi = pack2(of[s][dt][4 * p + 2], of[s][dt][4 * p + 3]);
                uint2 st = {lo, hi};
                *(uint2*)(orow + d) = st;
            }
        if (hh == 0) {
            float2 ml = {m2[s], lsum[s]};
            *(float2*)&ML[((size_t)(z * BH + bh) * TT + qrow) * 2] = ml;
        }
    }
}

// ---------------------------------------------------------------------------
// K3b: merge the split-K partials -> att (bf16, head-major cols).
// ---------------------------------------------------------------------------
__global__ __launch_bounds__(256)
void merge(const bf16* __restrict__ OP, const float* __restrict__ ML,
           bf16* __restrict__ att)
{
    const int idx = blockIdx.x * 256 + threadIdx.x;
    if (idx >= BH * TT * 16) return;
    const int quad = idx & 15;
    const int pair = idx >> 4;
    const int bh = pair / TT, row = pair % TT;
    const int b = bh / HH, h = bh % HH;
    const int d0 = quad * 4;

    float2 ml[NSPL];
    #pragma unroll
    for (int z = 0; z < NSPL; z++)
        ml[z] = *(const float2*)&ML[((size_t)(z * BH + bh) * TT + row) * 2];
    float M = ml[0].x;
    #pragma unroll
    for (int z = 1; z < NSPL; z++) M = fmaxf(M, ml[z].x);
    float wz[NSPL], den = 0.f;
    #pragma unroll
    for (int z = 0; z < NSPL; z++) {
        wz[z] = __builtin_amdgcn_exp2f(ml[z].x - M);
        den += ml[z].y * wz[z];
    }
    const float inv = 1.f / den;

    float o0 = 0.f, o1 = 0.f, o2 = 0.f, o3 = 0.f;
    #pragma unroll
    for (int z = 0; z < NSPL; z++) {
        const float s = wz[z] * inv;
        const uint2 a = *(const uint2*)&OP[((size_t)(z * BH + bh) * TT + row) * DH + d0];
        o0 += bu2f(a.x & 0xffffu) * s;
        o1 += bu2f(a.x >> 16)     * s;
        o2 += bu2f(a.y & 0xffffu) * s;
        o3 += bu2f(a.y >> 16)     * s;
    }
    uint2 st = {pack2(o0, o1), pack2(o2, o3)};
    *(uint2*)&att[((size_t)(b * TT + row) * CC) + h * DH + d0] = st;
}

// ---------------------------------------------------------------------------
// K4: output projection GEMM + bias, 128-row m-tiles, fp32 out.
// ---------------------------------------------------------------------------
__global__ __launch_bounds__(256)
void out_gemm(const bf16* __restrict__ att, const bf16* __restrict__ Wo_bf,
              const float* __restrict__ bo, float* __restrict__ out)
{
    const int m0 = blockIdx.x * 128;
    const int n0 = blockIdx.y * 64;
    const int w = threadIdx.x >> 6, lane = threadIdx.x & 63;
    const int lm = lane & 15, q4 = lane >> 4;

    const size_t ar0 = (size_t)(m0 + w * 16 + lm) * CC;
    floatx4 acc[2][4];
    #pragma unroll
    for (int st = 0; st < 2; st++)
        #pragma unroll
        for (int n = 0; n < 4; n++) acc[st][n] = (floatx4){0.f, 0.f, 0.f, 0.f};

    #pragma unroll 4
    for (int kc = 0; kc < CC / 32; kc++) {
        short8 a0 = *(const short8*)(att + ar0 + kc * 32 + q4 * 8);
        short8 a1 = *(const short8*)(att + ar0 + (size_t)64 * CC + kc * 32 + q4 * 8);
        #pragma unroll
        for (int n = 0; n < 4; n++) {
            short8 bfr = *(const short8*)(Wo_bf + (size_t)(n0 + n * 16 + lm) * CC + kc * 32 + q4 * 8);
            acc[0][n] = MFMA16(a0, bfr, acc[0][n]);
            acc[1][n] = MFMA16(a1, bfr, acc[1][n]);
        }
    }

    #pragma unroll
    for (int st = 0; st < 2; st++)
        #pragma unroll
        for (int n = 0; n < 4; n++) {
            const int o = n0 + n * 16 + lm;
            const float bias = bo[o];
            #pragma unroll
            for (int r = 0; r < 4; r++) {
                const int m = m0 + st * 64 + w * 16 + q4 * 4 + r;
                if (m < MF) out[(size_t)m * CC + o] = acc[st][n][r] + bias;
            }
        }
}

// ---------------------------------------------------------------------------
extern "C" void kernel_launch(void* const* d_in, const int* in_sizes, int n_in,
                              void* d_out, int out_size, void* d_ws, size_t ws_size,
                              hipStream_t stream)
{
    const float* x  = (const float*)d_in[0];
    const float* kq = (const float*)d_in[3];
    const float* kk = (const float*)d_in[4];
    const float* kv = (const float*)d_in[5];
    const float* gq = (const float*)d_in[6];
    const float* bq = (const float*)d_in[7];
    const float* mq = (const float*)d_in[8];
    const float* vq = (const float*)d_in[9];
    const float* gk = (const float*)d_in[10];
    const float* bk = (const float*)d_in[11];
    const float* mk = (const float*)d_in[12];
    const float* vk = (const float*)d_in[13];
    const float* gv = (const float*)d_in[14];
    const float* bv = (const float*)d_in[15];
    const float* mv = (const float*)d_in[16];
    const float* vv = (const float*)d_in[17];
    const float* Wq = (const float*)d_in[18];
    const float* Wk = (const float*)d_in[19];
    const float* Wv = (const float*)d_in[20];
    const float* Wo = (const float*)d_in[21];
    const float* bo = (const float*)d_in[22];

    char* ws = (char*)d_ws;
    const size_t SZ_CONV = (size_t)MP * CC * 2;        // 7,176,192
    const size_t SZ_Q    = (size_t)BH * TQP * DH * 2;  // 7,864,320
    const size_t SZ_K    = (size_t)BH * TP * DH * 2;   // 7,274,496
    const size_t SZ_W    = (size_t)CC * CC * 2;        //   294,912
    size_t off = 0;
    bf16* cq   = (bf16*)(ws + off); off += SZ_CONV;
    bf16* ck   = (bf16*)(ws + off); off += SZ_CONV;
    bf16* cv   = (bf16*)(ws + off); off += SZ_CONV;
    bf16* qb   = (bf16*)(ws + off); off += SZ_Q;
    bf16* kb   = (bf16*)(ws + off); off += SZ_K;
    bf16* vTb  = (bf16*)(ws + off); off += SZ_K;
    bf16* attb = (bf16*)(ws + off); off += SZ_CONV;
    bf16* wqb  = (bf16*)(ws + off); off += SZ_W;
    bf16* wkb  = (bf16*)(ws + off); off += SZ_W;
    bf16* wvb  = (bf16*)(ws + off); off += SZ_W;
    bf16* wob  = (bf16*)(ws + off); off += SZ_W;
    // flash partials: OP aliases cq..cv (dead after qkv_gemm), ML in tail
    bf16*  OP = (bf16*)ws;     // 2*24*2305*64*2 = 14,161,920 <= 3*SZ_CONV
    float* ML = (float*)(ws + off); off += (size_t)NSPL * BH * TT * 2 * 4;

    conv_bn<<<BN * 289, 384, 0, stream>>>(x, kq, kk, kv,
                                          gq, bq, mq, vq,
                                          gk, bk, mk, vk,
                                          gv, bv, mv, vv,
                                          Wq, Wk, Wv, Wo,
                                          wqb, wkb, wvb, wob,
                                          cq, ck, cv);
    qkv_gemm<<<dim3(40, 18), 256, 0, stream>>>(cq, ck, cv, wqb, wkb, wvb, qb, kb, vTb);
    flash<<<10 * NSPL * BH, 256, 0, stream>>>(qb, kb, vTb, OP, ML);
    merge<<<(BH * TT * 16 + 255) / 256, 256, 0, stream>>>(OP, ML, attb);
    out_gemm<<<dim3(MB2, 6), 256, 0, stream>>>(attb, wob, bo, (float*)d_out);
}

// Round 10
// 283.110 us; speedup vs baseline: 1.1657x; 1.0147x over previous
//
#include <hip/hip_runtime.h>
#include <hip/hip_bf16.h>

#define BN 4
#define TT 2305
#define CC 384
#define HH 6
#define DH 64
#define GW 48
#define BH (BN*HH)          // 24
#define TP 2368             // 37*64, padded T for K/V
#define TQP 2560            // q buffer rows (10*256 coverage)
#define MF 9220             // BN*TT flattened tokens
#define MP 9344             // 73*128 padded
#define MB2 73              // m-blocks of 128 in out_gemm
#define NSPL 2              // flash split-K
#define C2 0.07362223f      // 384^-0.5 * log2(e)

typedef __hip_bfloat16 bf16;
typedef __attribute__((ext_vector_type(8))) short short8;
typedef __attribute__((ext_vector_type(4))) float floatx4;
typedef __attribute__((ext_vector_type(16))) float floatx16;

#define MFMA16(a,b,c) __builtin_amdgcn_mfma_f32_16x16x32_bf16((a),(b),(c),0,0,0)
#define MFMA32(a,b,c) __builtin_amdgcn_mfma_f32_32x32x16_bf16((a),(b),(c),0,0,0)

__device__ __forceinline__ unsigned pack2(float a, float b) {
    bf16 lo = __float2bfloat16(a);
    bf16 hi = __float2bfloat16(b);
    unsigned short ul = *reinterpret_cast<unsigned short*>(&lo);
    unsigned short uh = *reinterpret_cast<unsigned short*>(&hi);
    return (unsigned)ul | ((unsigned)uh << 16);
}
__device__ __forceinline__ float bu2f(unsigned u16) {
    unsigned v = u16 << 16;
    return *reinterpret_cast<float*>(&v);
}

// ---------------------------------------------------------------------------
// K1: depthwise conv3x3 + BN (+ cls passthrough) + fused fp32->bf16 weight cvt.
// ---------------------------------------------------------------------------
__global__ __launch_bounds__(384)
void conv_bn(const float* __restrict__ x,
             const float* __restrict__ kq, const float* __restrict__ kk, const float* __restrict__ kv,
             const float* __restrict__ gq, const float* __restrict__ bq, const float* __restrict__ mq, const float* __restrict__ vq,
             const float* __restrict__ gk, const float* __restrict__ bk, const float* __restrict__ mk, const float* __restrict__ vk,
             const float* __restrict__ gv, const float* __restrict__ bv, const float* __restrict__ mv, const float* __restrict__ vv,
             const float* __restrict__ Wq, const float* __restrict__ Wk,
             const float* __restrict__ Wv, const float* __restrict__ Wo,
             bf16* __restrict__ wqb, bf16* __restrict__ wkb,
             bf16* __restrict__ wvb, bf16* __restrict__ wob,
             bf16* __restrict__ cq, bf16* __restrict__ ck, bf16* __restrict__ cv)
{
    // fused weight conversion (first 384 blocks cover 147456 elems)
    {
        const int i = blockIdx.x * 384 + threadIdx.x;
        if (i < CC * CC) {
            wqb[i] = __float2bfloat16(Wq[i]);
            wkb[i] = __float2bfloat16(Wk[i]);
            wvb[i] = __float2bfloat16(Wv[i]);
            wob[i] = __float2bfloat16(Wo[i]);
        }
    }

    const int n = blockIdx.x;
    const int b = n / 289;
    const int t0 = (n % 289) * 8;
    const int c = threadIdx.x;
    const size_t xbase = (size_t)b * TT * CC;

    const float sq = gq[c] * rsqrtf(vq[c] + 1e-5f), oq = bq[c] - mq[c] * sq;
    const float sk = gk[c] * rsqrtf(vk[c] + 1e-5f), ok = bk[c] - mk[c] * sk;
    const float sv = gv[c] * rsqrtf(vv[c] + 1e-5f), ov = bv[c] - mv[c] * sv;
    float wq9[9], wk9[9], wv9[9];
    #pragma unroll
    for (int u = 0; u < 9; u++) {
        wq9[u] = kq[c * 9 + u]; wk9[u] = kk[c * 9 + u]; wv9[u] = kv[c * 9 + u];
    }

    for (int g = 0; g < 8; g++) {
        const int t = t0 + g;
        if (t >= TT) break;
        const size_t mrow = (size_t)(b * TT + t) * CC + c;
        if (t == 0) {
            bf16 xv = __float2bfloat16(x[xbase + c]);
            cq[mrow] = xv; ck[mrow] = xv; cv[mrow] = xv;
        } else {
            const int s = t - 1, i = s / GW, j = s % GW;
            float aq = 0.f, ak = 0.f, av = 0.f;
            #pragma unroll
            for (int di = 0; di < 3; di++) {
                int ii = i + di - 1;
                if (ii < 0 || ii >= GW) continue;
                #pragma unroll
                for (int dj = 0; dj < 3; dj++) {
                    int jj = j + dj - 1;
                    if (jj < 0 || jj >= GW) continue;
                    float xv = x[xbase + (size_t)(1 + ii * GW + jj) * CC + c];
                    int u = di * 3 + dj;
                    aq += xv * wq9[u]; ak += xv * wk9[u]; av += xv * wv9[u];
                }
            }
            cq[mrow] = __float2bfloat16(aq * sq + oq);
            ck[mrow] = __float2bfloat16(ak * sk + ok);
            cv[mrow] = __float2bfloat16(av * sv + ov);
        }
    }
}

// ---------------------------------------------------------------------------
// K2: QKV projection GEMM, per-batch 256-row m-tiles (4 strips share B-frags).
// grid = (40 = 4 batches x 10 tiles, 18 n-tiles). V gets an LDS-transpose
// epilogue for coalesced vT stores.
// ---------------------------------------------------------------------------
__global__ __launch_bounds__(256)
void qkv_gemm(const bf16* __restrict__ cq, const bf16* __restrict__ ck, const bf16* __restrict__ cv,
              const bf16* __restrict__ Wq, const bf16* __restrict__ Wk, const bf16* __restrict__ Wv,
              bf16* __restrict__ q, bf16* __restrict__ k, bf16* __restrict__ vT)
{
    const int bt = blockIdx.x;
    const int b = bt / 10;
    const int m0 = (bt % 10) * 256;       // token index within batch
    const int n0 = blockIdx.y * 64;
    const int w = threadIdx.x >> 6, lane = threadIdx.x & 63;
    const int lm = lane & 15, q4 = lane >> 4;
    const int which = n0 / CC;
    const int obase = n0 % CC;
    const bf16* A = (which == 0) ? cq : (which == 1) ? ck : cv;
    const bf16* W = (which == 0) ? Wq : (which == 1) ? Wk : Wv;

    __shared__ __align__(16) bf16 TR[64 * 264];

    size_t arow[4];
    #pragma unroll
    for (int st = 0; st < 4; st++) {
        int t = m0 + st * 64 + w * 16 + lm;
        if (t >= TT) t = TT - 1;          // clamp; masked at store
        arow[st] = (size_t)(b * TT + t) * CC;
    }

    floatx4 acc[4][4];
    #pragma unroll
    for (int st = 0; st < 4; st++)
        #pragma unroll
        for (int n = 0; n < 4; n++) acc[st][n] = (floatx4){0.f, 0.f, 0.f, 0.f};

    #pragma unroll 2
    for (int kc = 0; kc < CC / 32; kc++) {
        short8 a[4];
        #pragma unroll
        for (int st = 0; st < 4; st++)
            a[st] = *(const short8*)(A + arow[st] + kc * 32 + q4 * 8);
        #pragma unroll
        for (int n = 0; n < 4; n++) {
            short8 bfr = *(const short8*)(W + (size_t)(obase + n * 16 + lm) * CC + kc * 32 + q4 * 8);
            #pragma unroll
            for (int st = 0; st < 4; st++)
                acc[st][n] = MFMA16(a[st], bfr, acc[st][n]);
        }
    }

    if (which == 2) {
        // transpose via LDS: TR[o_local][m_local], stride 264
        #pragma unroll
        for (int st = 0; st < 4; st++)
            #pragma unroll
            for (int n = 0; n < 4; n++) {
                const int ol = n * 16 + lm;
                const int ml = st * 64 + w * 16 + q4 * 4;
                uint2 pkd = { pack2(acc[st][n][0], acc[st][n][1]),
                              pack2(acc[st][n][2], acc[st][n][3]) };
                *(uint2*)&TR[ol * 264 + ml] = pkd;
            }
        __syncthreads();
        const int h = obase >> 6;
        const int o = threadIdx.x >> 2;       // d in [0,64)
        const int seg = threadIdx.x & 3;      // 64 m per seg
        const size_t vrow = ((size_t)(b * HH + h) * DH + o) * TP;
        #pragma unroll
        for (int j = 0; j < 8; j++) {
            const int ml = seg * 64 + j * 8;
            const int t = m0 + ml;
            uint4 val = *(const uint4*)&TR[o * 264 + ml];
            if (t + 8 <= TT) {
                *(uint4*)(vT + vrow + t) = val;
            } else if (t < TT) {
                const bf16* pv = (const bf16*)&val;
                for (int e = 0; e < 8 && t + e < TT; e++) vT[vrow + t + e] = pv[e];
            }
        }
    } else {
        #pragma unroll
        for (int st = 0; st < 4; st++)
            #pragma unroll
            for (int n = 0; n < 4; n++) {
                const int o = obase + n * 16 + lm;
                const int h = o >> 6, d = o & 63;
                #pragma unroll
                for (int r = 0; r < 4; r++) {
                    const int t = m0 + st * 64 + w * 16 + q4 * 4 + r;
                    if (t >= TT) continue;
                    bf16 val = __float2bfloat16(acc[st][n][r]);
                    if (which == 0)
                        q[((size_t)(b * HH + h) * TQP + t) * DH + d] = val;
                    else
                        k[((size_t)(b * HH + h) * TP + t) * DH + d] = val;
                }
            }
    }
}

// ---------------------------------------------------------------------------
// K3: flash attention, split-K x2, LDS-FREE: A/B fragments are 16B-contiguous
// in the global K / vT layouts, loaded via global_load_dwordx4. With the
// XCD-affinity swizzle (id%8 == bh%8) K/V is L2-resident and the 16 KB
// per-tile working set is L1-resident, so the 4-wave reuse is served by L1.
// No barriers, no LDS pipe, no bank conflicts; waves run decoupled.
// Writes unnormalized O (bf16) + m,l (fp32).
// ---------------------------------------------------------------------------
__global__ __launch_bounds__(256, 2)
void flash(const bf16* __restrict__ q, const bf16* __restrict__ k,
           const bf16* __restrict__ vT, bf16* __restrict__ OP, float* __restrict__ ML)
{
    const int id = blockIdx.x;
    const int bh = id % BH;
    const int rest = id / BH;
    const int z = rest % NSPL;
    const int qt = rest / NSPL;
    const int tid = threadIdx.x;
    const int w = tid >> 6, lane = tid & 63;
    const int q31 = lane & 31, hh = lane >> 5;
    const int q0 = qt * 256 + w * 64;
    const size_t kbase = (size_t)bh * TP * DH;
    const size_t qbase = (size_t)bh * TQP * DH;

    short8 qf[2][4];
    #pragma unroll
    for (int s = 0; s < 2; s++) {
        const bf16* qrow = q + qbase + (size_t)(q0 + s * 32 + q31) * DH;
        #pragma unroll
        for (int kc = 0; kc < 4; kc++)
            qf[s][kc] = *(const short8*)(qrow + kc * 16 + hh * 8);
    }

    floatx16 of[2][2];
    #pragma unroll
    for (int s = 0; s < 2; s++)
        #pragma unroll
        for (int dt = 0; dt < 2; dt++)
            #pragma unroll
            for (int r = 0; r < 16; r++) of[s][dt][r] = 0.f;
    float m2[2] = {-1e30f, -1e30f}, lsum[2] = {0.f, 0.f};

    const int tstart = z ? 19 : 0;
    const int tend   = z ? 37 : 19;

    for (int tc = tstart; tc < tend; tc++) {
        const int t0 = tc * 64;
        const bf16* kt = k + kbase + (size_t)t0 * DH;   // K[t0+row][*]
        const bf16* vt = vT + kbase + t0;               // V^T[row][t0+*]

        // A-fragments straight from global (16B chunks, L1/L2-resident)
        short8 ka[2][4], va[2][4];
        #pragma unroll
        for (int mt = 0; mt < 2; mt++)
            #pragma unroll
            for (int kc = 0; kc < 4; kc++) {
                const int row = mt * 32 + q31, c = 2 * kc + hh;
                ka[mt][kc] = *(const short8*)(kt + (size_t)row * DH + c * 8);
                va[mt][kc] = *(const short8*)(vt + (size_t)row * TP + c * 8);
            }
        const bool tail = (t0 + 64 > TT);

        #pragma unroll
        for (int s = 0; s < 2; s++) {
            floatx16 sv[2];
            #pragma unroll
            for (int mt = 0; mt < 2; mt++)
                #pragma unroll
                for (int r = 0; r < 16; r++) sv[mt][r] = 0.f;
            #pragma unroll
            for (int kc = 0; kc < 4; kc++) {
                sv[0] = MFMA32(ka[0][kc], qf[s][kc], sv[0]);
                sv[1] = MFMA32(ka[1][kc], qf[s][kc], sv[1]);
            }
            if (tail) {
                #pragma unroll
                for (int mt = 0; mt < 2; mt++)
                    #pragma unroll
                    for (int r = 0; r < 16; r++) {
                        const int tl = t0 + mt * 32 + (r & 3) + 8 * (r >> 2) + 4 * hh;
                        if (tl >= TT) sv[mt][r] = -1e30f;
                    }
            }
            float rm = sv[0][0];
            #pragma unroll
            for (int r = 1; r < 16; r++) rm = fmaxf(rm, sv[0][r]);
            #pragma unroll
            for (int r = 0; r < 16; r++) rm = fmaxf(rm, sv[1][r]);
            rm = fmaxf(rm, __shfl_xor(rm, 32));
            const float mn = fmaxf(m2[s], rm * C2);
            const float alpha = __builtin_amdgcn_exp2f(m2[s] - mn);
            m2[s] = mn;
            const float negm = -mn;
            float rs = 0.f;
            unsigned pk[2][8];
            #pragma unroll
            for (int mt = 0; mt < 2; mt++)
                #pragma unroll
                for (int p = 0; p < 8; p++) {
                    const float p0 = __builtin_amdgcn_exp2f(fmaf(sv[mt][2 * p], C2, negm));
                    const float p1 = __builtin_amdgcn_exp2f(fmaf(sv[mt][2 * p + 1], C2, negm));
                    rs += p0 + p1;
                    pk[mt][p] = pack2(p0, p1);
                }
            rs += __shfl_xor(rs, 32);
            lsum[s] = lsum[s] * alpha + rs;
            #pragma unroll
            for (int dt = 0; dt < 2; dt++)
                #pragma unroll
                for (int r = 0; r < 16; r++) of[s][dt][r] *= alpha;

            #pragma unroll
            for (int kc = 0; kc < 4; kc++) {
                const int u0 = 2 * kc, u1 = 2 * kc + 1;
                const unsigned P0a = pk[u0 >> 2][2 * (u0 & 3)];
                const unsigned P0b = pk[u0 >> 2][2 * (u0 & 3) + 1];
                const unsigned P1a = pk[u1 >> 2][2 * (u1 & 3)];
                const unsigned P1b = pk[u1 >> 2][2 * (u1 & 3) + 1];
                const unsigned X1 = hh ? P0a : P1a;
                const unsigned X2 = hh ? P0b : P1b;
                const unsigned Y1 = __shfl_xor(X1, 32);
                const unsigned Y2 = __shfl_xor(X2, 32);
                unsigned dw[4];
                dw[0] = hh ? Y1 : P0a;
                dw[1] = hh ? Y2 : P0b;
                dw[2] = hh ? P1a : Y1;
                dw[3] = hh ? P1b : Y2;
                short8 pb = *reinterpret_cast<short8*>(dw);
                of[s][0] = MFMA32(va[0][kc], pb, of[s][0]);
                of[s][1] = MFMA32(va[1][kc], pb, of[s][1]);
            }
        }
    }

    // store unnormalized partials (rows packed to TT per (z,bh))
    #pragma unroll
    for (int s = 0; s < 2; s++) {
        const int qrow = q0 + s * 32 + q31;
        if (qrow >= TT) continue;
        bf16* orow = OP + ((size_t)(z * BH + bh) * TT + qrow) * DH;
        #pragma unroll
        for (int dt = 0; dt < 2; dt++)
            #pragma unroll
            for (int p = 0; p < 4; p++) {
                const int d = dt * 32 + 8 * p + 4 * hh;
                unsigned lo = pack2(of[s][dt][4 * p], of[s][dt][4 * p + 1]);
                unsigned hi = pack2(of[s][dt][4 * p + 2], of[s][dt][4 * p + 3]);
                uint2 st = {lo, hi};
                *(uint2*)(orow + d) = st;
            }
        if (hh == 0) {
            float2 ml = {m2[s], lsum[s]};
            *(float2*)&ML[((size_t)(z * BH + bh) * TT + qrow) * 2] = ml;
        }
    }
}

// ---------------------------------------------------------------------------
// K3b: merge the split-K partials -> att (bf16, head-major cols).
// ---------------------------------------------------------------------------
__global__ __launch_bounds__(256)
void merge(const bf16* __restrict__ OP, const float* __restrict__ ML,
           bf16* __restrict__ att)
{
    const int idx = blockIdx.x * 256 + threadIdx.x;
    if (idx >= BH * TT * 16) return;
    const int quad = idx & 15;
    const int pair = idx >> 4;
    const int bh = pair / TT, row = pair % TT;
    const int b = bh / HH, h = bh % HH;
    const int d0 = quad * 4;

    float2 ml[NSPL];
    #pragma unroll
    for (int z = 0; z < NSPL; z++)
        ml[z] = *(const float2*)&ML[((size_t)(z * BH + bh) * TT + row) * 2];
    float M = ml[0].x;
    #pragma unroll
    for (int z = 1; z < NSPL; z++) M = fmaxf(M, ml[z].x);
    float wz[NSPL], den = 0.f;
    #pragma unroll
    for (int z = 0; z < NSPL; z++) {
        wz[z] = __builtin_amdgcn_exp2f(ml[z].x - M);
        den += ml[z].y * wz[z];
    }
    const float inv = 1.f / den;

    float o0 = 0.f, o1 = 0.f, o2 = 0.f, o3 = 0.f;
    #pragma unroll
    for (int z = 0; z < NSPL; z++) {
        const float s = wz[z] * inv;
        const uint2 a = *(const uint2*)&OP[((size_t)(z * BH + bh) * TT + row) * DH + d0];
        o0 += bu2f(a.x & 0xffffu) * s;
        o1 += bu2f(a.x >> 16)     * s;
        o2 += bu2f(a.y & 0xffffu) * s;
        o3 += bu2f(a.y >> 16)     * s;
    }
    uint2 st = {pack2(o0, o1), pack2(o2, o3)};
    *(uint2*)&att[((size_t)(b * TT + row) * CC) + h * DH + d0] = st;
}

// ---------------------------------------------------------------------------
// K4: output projection GEMM + bias, 128-row m-tiles, fp32 out.
// ---------------------------------------------------------------------------
__global__ __launch_bounds__(256)
void out_gemm(const bf16* __restrict__ att, const bf16* __restrict__ Wo_bf,
              const float* __restrict__ bo, float* __restrict__ out)
{
    const int m0 = blockIdx.x * 128;
    const int n0 = blockIdx.y * 64;
    const int w = threadIdx.x >> 6, lane = threadIdx.x & 63;
    const int lm = lane & 15, q4 = lane >> 4;

    const size_t ar0 = (size_t)(m0 + w * 16 + lm) * CC;
    floatx4 acc[2][4];
    #pragma unroll
    for (int st = 0; st < 2; st++)
        #pragma unroll
        for (int n = 0; n < 4; n++) acc[st][n] = (floatx4){0.f, 0.f, 0.f, 0.f};

    #pragma unroll 4
    for (int kc = 0; kc < CC / 32; kc++) {
        short8 a0 = *(const short8*)(att + ar0 + kc * 32 + q4 * 8);
        short8 a1 = *(const short8*)(att + ar0 + (size_t)64 * CC + kc * 32 + q4 * 8);
        #pragma unroll
        for (int n = 0; n < 4; n++) {
            short8 bfr = *(const short8*)(Wo_bf + (size_t)(n0 + n * 16 + lm) * CC + kc * 32 + q4 * 8);
            acc[0][n] = MFMA16(a0, bfr, acc[0][n]);
            acc[1][n] = MFMA16(a1, bfr, acc[1][n]);
        }
    }

    #pragma unroll
    for (int st = 0; st < 2; st++)
        #pragma unroll
        for (int n = 0; n < 4; n++) {
            const int o = n0 + n * 16 + lm;
            const float bias = bo[o];
            #pragma unroll
            for (int r = 0; r < 4; r++) {
                const int m = m0 + st * 64 + w * 16 + q4 * 4 + r;
                if (m < MF) out[(size_t)m * CC + o] = acc[st][n][r] + bias;
            }
        }
}

// ---------------------------------------------------------------------------
extern "C" void kernel_launch(void* const* d_in, const int* in_sizes, int n_in,
                              void* d_out, int out_size, void* d_ws, size_t ws_size,
                              hipStream_t stream)
{
    const float* x  = (const float*)d_in[0];
    const float* kq = (const float*)d_in[3];
    const float* kk = (const float*)d_in[4];
    const float* kv = (const float*)d_in[5];
    const float* gq = (const float*)d_in[6];
    const float* bq = (const float*)d_in[7];
    const float* mq = (const float*)d_in[8];
    const float* vq = (const float*)d_in[9];
    const float* gk = (const float*)d_in[10];
    const float* bk = (const float*)d_in[11];
    const float* mk = (const float*)d_in[12];
    const float* vk = (const float*)d_in[13];
    const float* gv = (const float*)d_in[14];
    const float* bv = (const float*)d_in[15];
    const float* mv = (const float*)d_in[16];
    const float* vv = (const float*)d_in[17];
    const float* Wq = (const float*)d_in[18];
    const float* Wk = (const float*)d_in[19];
    const float* Wv = (const float*)d_in[20];
    const float* Wo = (const float*)d_in[21];
    const float* bo = (const float*)d_in[22];

    char* ws = (char*)d_ws;
    const size_t SZ_CONV = (size_t)MP * CC * 2;        // 7,176,192
    const size_t SZ_Q    = (size_t)BH * TQP * DH * 2;  // 7,864,320
    const size_t SZ_K    = (size_t)BH * TP * DH * 2;   // 7,274,496
    const size_t SZ_W    = (size_t)CC * CC * 2;        //   294,912
    size_t off = 0;
    bf16* cq   = (bf16*)(ws + off); off += SZ_CONV;
    bf16* ck   = (bf16*)(ws + off); off += SZ_CONV;
    bf16* cv   = (bf16*)(ws + off); off += SZ_CONV;
    bf16* qb   = (bf16*)(ws + off); off += SZ_Q;
    bf16* kb   = (bf16*)(ws + off); off += SZ_K;
    bf16* vTb  = (bf16*)(ws + off); off += SZ_K;
    bf16* attb = (bf16*)(ws + off); off += SZ_CONV;
    bf16* wqb  = (bf16*)(ws + off); off += SZ_W;
    bf16* wkb  = (bf16*)(ws + off); off += SZ_W;
    bf16* wvb  = (bf16*)(ws + off); off += SZ_W;
    bf16* wob  = (bf16*)(ws + off); off += SZ_W;
    // flash partials: OP aliases cq..cv (dead after qkv_gemm), ML in tail
    bf16*  OP = (bf16*)ws;     // 2*24*2305*64*2 = 14,161,920 <= 3*SZ_CONV
    float* ML = (float*)(ws + off); off += (size_t)NSPL * BH * TT * 2 * 4;

    conv_bn<<<BN * 289, 384, 0, stream>>>(x, kq, kk, kv,
                                          gq, bq, mq, vq,
                                          gk, bk, mk, vk,
                                          gv, bv, mv, vv,
                                          Wq, Wk, Wv, Wo,
                                          wqb, wkb, wvb, wob,
                                          cq, ck, cv);
    qkv_gemm<<<dim3(40, 18), 256, 0, stream>>>(cq, ck, cv, wqb, wkb, wvb, qb, kb, vTb);
    flash<<<10 * NSPL * BH, 256, 0, stream>>>(qb, kb, vTb, OP, ML);
    merge<<<(BH * TT * 16 + 255) / 256, 256, 0, stream>>>(OP, ML, attb);
    out_gemm<<<dim3(MB2, 6), 256, 0, stream>>>(attb, wob, bo, (float*)d_out);
}